// Round 4
// baseline (135.656 us; speedup 1.0000x reference)
//
#include <hip/hip_runtime.h>
#include <hip/hip_bf16.h>

// ---- problem constants ----
#define HID   1024
#define NEXP  8
#define NPAIR 4096                       // TOKENS * TOPK
#define BMPAD 128                        // segment padding = BM
#define PERM_MAX (NPAIR + NEXP * BMPAD)  // 5120
#define MT_MAX (PERM_MAX / 128)          // 40 M-tiles

typedef unsigned short u16;
typedef __attribute__((ext_vector_type(8))) short bf16x8;
typedef __attribute__((ext_vector_type(4))) float f32x4;
typedef __attribute__((ext_vector_type(4))) unsigned short us4;

static __device__ __forceinline__ u16 f2bf(float f) {
  union { float f; unsigned u; } v; v.f = f;
  unsigned u = v.u;
  unsigned r = (u + 0x7fffu + ((u >> 16) & 1u)) >> 16;
  return (u16)r;
}

// pack 2 f32 -> 2 bf16 (v_cvt_pk_bf16_f32)
static __device__ __forceinline__ unsigned pk2(float a, float b) {
  __hip_bfloat162 h = __float22bfloat162_rn(make_float2(a, b));
  union { __hip_bfloat162 h; unsigned u; } c; c.h = h; return c.u;
}

// 8 f32 -> bf16x8 fragment
static __device__ __forceinline__ bf16x8 cvt8(f32x4 a, f32x4 b) {
  union { unsigned u[4]; bf16x8 v; } r;
  r.u[0] = pk2(a[0], a[1]); r.u[1] = pk2(a[2], a[3]);
  r.u[2] = pk2(b[0], b[1]); r.u[3] = pk2(b[2], b[3]);
  return r.v;
}

static __device__ __forceinline__ void gload16(const void* g, void* l) {
  __builtin_amdgcn_global_load_lds(
      (const __attribute__((address_space(1))) unsigned int*)g,
      (__attribute__((address_space(3))) unsigned int*)l, 16, 0, 0);
}

static __device__ __forceinline__ f32x4 mfma_bf16(bf16x8 a, bf16x8 b, f32x4 c) {
  return __builtin_amdgcn_mfma_f32_16x16x32_bf16(a, b, c, 0, 0, 0);
}

// ---- prep: zero d_out, convert x -> bf16 ----
__global__ __launch_bounds__(256) void k_prep(const float* __restrict__ x,
                                              u16* __restrict__ xb,
                                              float* __restrict__ out) {
  int i = blockIdx.x * 256 + threadIdx.x;
  int base = i * 8;
  f32x4 v0 = *(const f32x4*)(x + base);
  f32x4 v1 = *(const f32x4*)(x + base + 4);
  us4 a = { f2bf(v0[0]), f2bf(v0[1]), f2bf(v0[2]), f2bf(v0[3]) };
  us4 b = { f2bf(v1[0]), f2bf(v1[1]), f2bf(v1[2]), f2bf(v1[3]) };
  *(us4*)(xb + base)     = a;
  *(us4*)(xb + base + 4) = b;
  f32x4 z = {0.f, 0.f, 0.f, 0.f};
  *(f32x4*)(out + base)     = z;
  *(f32x4*)(out + base + 4) = z;
}

// ---- routing ----
__global__ __launch_bounds__(256) void k_route(const int* __restrict__ sel,
                                               int* __restrict__ hdr,
                                               int* __restrict__ perm) {
  __shared__ int cnt[NEXP];
  __shared__ int cur[NEXP];
  int tid = threadIdx.x;
  if (tid < NEXP) cnt[tid] = 0;
  __syncthreads();
  for (int p = tid; p < NPAIR; p += 256) atomicAdd(&cnt[sel[p]], 1);
  __syncthreads();
  if (tid == 0) {
    int acc = 0;
    for (int e = 0; e < NEXP; e++) {
      hdr[e] = acc;
      cur[e] = acc;
      acc += (cnt[e] + 127) & ~127;
    }
    hdr[NEXP] = acc;
  }
  __syncthreads();
  for (int i = tid; i < PERM_MAX; i += 256) perm[i] = -1;
  __syncthreads();
  for (int p = tid; p < NPAIR; p += 256) {
    int e = sel[p];
    int slot = atomicAdd(&cur[e], 1);
    perm[slot] = p;
  }
}

// ==== GEMM 1: gate+up fused, SwiGLU -> hbuf ====
// BM=128, BN=64 (per matrix), BK=64. 4 waves, pure N-split (wave wv owns
// cols wv*16..wv*16+15 of each matrix). A in LDS (2-buf, gload_lds); B
// fragments loaded f32 from global per-lane, cvt_pk -> bf16 in regs.
__global__ __launch_bounds__(256, 3) void k_gateup(const u16* __restrict__ xb,
                                                   const float* __restrict__ gw,
                                                   const float* __restrict__ uw,
                                                   const int* __restrict__ hdr,
                                                   const int* __restrict__ perm,
                                                   u16* __restrict__ hbuf) {
  __shared__ __align__(16) u16 lA[2][128 * 64];   // 2 x 16 KB

  const int tid = threadIdx.x, lane = tid & 63, wv = tid >> 6;
  // XCD-locality swizzle: xcd = wgid&7; consecutive M-tiles of the same
  // (expert, N-tile) are 2 slots apart on the same XCD.
  const int wgid = blockIdx.x;
  const int slot = wgid >> 3;
  const int nt = ((slot & 1) << 3) | (wgid & 7);
  const int mt = slot >> 1;
  const int n0 = nt * 64, m0 = mt * 128;
  if (m0 >= hdr[NEXP]) return;
  int e = 0;
  #pragma unroll
  for (int k = 1; k < NEXP; k++) if (m0 >= hdr[k]) e = k;

  // A staging: 16 x 1KiB issues (4/thread). LDS linear; source inverse-swizzled.
  const u16* srcA[4]; int dstAo[4];
  #pragma unroll
  for (int j = 0; j < 4; j++) {
    int rt = wv * 32 + j * 8 + (lane >> 3);
    int p = perm[m0 + rt];
    int tok = (p < 0) ? 0 : (p >> 1);
    int sw = (lane & 7) ^ (rt & 7);
    srcA[j] = xb + (size_t)tok * HID + sw * 8;
    dstAo[j] = (wv * 32 + j * 8) * 64;
  }

  const int fr = lane & 15, fq = lane >> 4;
  // B pointers: lane-fixed row, fq-selected k-octet.
  const size_t eb = (size_t)e * (1 << 20);
  const int brow = n0 + wv * 16 + fr;
  const float* pG = gw + eb + (size_t)brow * HID + fq * 8;
  const float* pU = uw + eb + (size_t)brow * HID + fq * 8;

  f32x4 ng[2][2], nu[2][2];     // staged f32 for next K-step [kk2][half]
  bf16x8 fg[2], fu[2];          // current converted fragments
  f32x4 ag[8], au[8];
  #pragma unroll
  for (int i = 0; i < 8; i++) {
    ag[i] = (f32x4){0.f, 0.f, 0.f, 0.f};
    au[i] = (f32x4){0.f, 0.f, 0.f, 0.f};
  }

#define GU_GLA(B, K0) {                                                        \
    _Pragma("unroll") for (int j = 0; j < 4; j++)                              \
      gload16(srcA[j] + (K0), &lA[B][dstAo[j]]); }

#define GU_LOADB(K0) {                                                         \
    _Pragma("unroll") for (int kk2 = 0; kk2 < 2; kk2++) {                      \
      ng[kk2][0] = *(const f32x4*)(pG + (K0) + kk2 * 32);                      \
      ng[kk2][1] = *(const f32x4*)(pG + (K0) + kk2 * 32 + 4);                  \
      nu[kk2][0] = *(const f32x4*)(pU + (K0) + kk2 * 32);                      \
      nu[kk2][1] = *(const f32x4*)(pU + (K0) + kk2 * 32 + 4);                  \
    } }

#define GU_CVTB() {                                                            \
    fg[0] = cvt8(ng[0][0], ng[0][1]); fg[1] = cvt8(ng[1][0], ng[1][1]);        \
    fu[0] = cvt8(nu[0][0], nu[0][1]); fu[1] = cvt8(nu[1][0], nu[1][1]); }

#define GU_COMP(B) {                                                           \
    _Pragma("unroll") for (int kk2 = 0; kk2 < 2; kk2++) {                      \
      _Pragma("unroll") for (int m2 = 0; m2 < 8; m2++) {                       \
        int r = m2 * 16 + fr, q = kk2 * 4 + fq;                                \
        bf16x8 af = *(const bf16x8*)&lA[B][r * 64 + (q ^ (r & 7)) * 8];        \
        ag[m2] = mfma_bf16(af, fg[kk2], ag[m2]);                               \
        au[m2] = mfma_bf16(af, fu[kk2], au[m2]);                               \
      }                                                                        \
    } }

  GU_GLA(0, 0);
  GU_LOADB(0);
  __syncthreads();
  GU_CVTB();
  for (int kk = 0; kk < 16; kk += 2) {
    GU_GLA(1, (kk + 1) * 64);
    GU_LOADB((kk + 1) * 64);
    GU_COMP(0);
    __syncthreads();
    GU_CVTB();
    if (kk + 2 < 16) { GU_GLA(0, (kk + 2) * 64); GU_LOADB((kk + 2) * 64); }
    GU_COMP(1);
    __syncthreads();
    if (kk + 2 < 16) GU_CVTB();
  }
#undef GU_GLA
#undef GU_LOADB
#undef GU_CVTB
#undef GU_COMP

  // epilogue: h = silu(g) * u -> bf16
  #pragma unroll
  for (int m2 = 0; m2 < 8; m2++)
    #pragma unroll
    for (int q = 0; q < 4; q++) {
      int row = m0 + m2 * 16 + fq * 4 + q;
      int col = n0 + wv * 16 + fr;
      float g = ag[m2][q];
      float u = au[m2][q];
      float h = (g / (1.0f + __expf(-g))) * u;
      hbuf[(size_t)row * HID + col] = f2bf(h);
    }
}

// ==== GEMM 2: down, weighted atomic scatter ====
// BM=128, BN=128, BK=64. 4 waves N-split; per wave 2 N-reps of 16.
__global__ __launch_bounds__(256, 3) void k_down(const u16* __restrict__ hbuf,
                                                 const float* __restrict__ dw,
                                                 const int* __restrict__ hdr,
                                                 const int* __restrict__ perm,
                                                 const float* __restrict__ rw,
                                                 float* __restrict__ out) {
  __shared__ __align__(16) u16 lA[2][128 * 64];   // 2 x 16 KB

  const int tid = threadIdx.x, lane = tid & 63, wv = tid >> 6;
  const int wgid = blockIdx.x;
  const int nt = wgid & 7;
  const int mt = wgid >> 3;
  const int n0 = nt * 128, m0 = mt * 128;
  if (m0 >= hdr[NEXP]) return;
  int e = 0;
  #pragma unroll
  for (int k = 1; k < NEXP; k++) if (m0 >= hdr[k]) e = k;

  const u16* srcA[4]; int dstAo[4];
  #pragma unroll
  for (int j = 0; j < 4; j++) {
    int rt = wv * 32 + j * 8 + (lane >> 3);
    int sw = (lane & 7) ^ (rt & 7);
    srcA[j] = hbuf + (size_t)(m0 + rt) * HID + sw * 8;
    dstAo[j] = (wv * 32 + j * 8) * 64;
  }

  const int fr = lane & 15, fq = lane >> 4;
  const size_t eb = (size_t)e * (1 << 20);
  const float* pB[2];
  #pragma unroll
  for (int n2 = 0; n2 < 2; n2++) {
    int brow = n0 + wv * 32 + n2 * 16 + fr;
    pB[n2] = dw + eb + (size_t)brow * HID + fq * 8;
  }

  f32x4 nb[2][2][2];            // [n2][kk2][half]
  bf16x8 fb[2][2];              // [n2][kk2]
  f32x4 acc[8][2];
  #pragma unroll
  for (int i = 0; i < 8; i++)
    #pragma unroll
    for (int j = 0; j < 2; j++) acc[i][j] = (f32x4){0.f, 0.f, 0.f, 0.f};

#define DN_GLA(B, K0) {                                                        \
    _Pragma("unroll") for (int j = 0; j < 4; j++)                              \
      gload16(srcA[j] + (K0), &lA[B][dstAo[j]]); }

#define DN_LOADB(K0) {                                                         \
    _Pragma("unroll") for (int n2 = 0; n2 < 2; n2++)                           \
      _Pragma("unroll") for (int kk2 = 0; kk2 < 2; kk2++) {                    \
        nb[n2][kk2][0] = *(const f32x4*)(pB[n2] + (K0) + kk2 * 32);            \
        nb[n2][kk2][1] = *(const f32x4*)(pB[n2] + (K0) + kk2 * 32 + 4);        \
      } }

#define DN_CVTB() {                                                            \
    _Pragma("unroll") for (int n2 = 0; n2 < 2; n2++) {                         \
      fb[n2][0] = cvt8(nb[n2][0][0], nb[n2][0][1]);                            \
      fb[n2][1] = cvt8(nb[n2][1][0], nb[n2][1][1]); } }

#define DN_COMP(B) {                                                           \
    _Pragma("unroll") for (int kk2 = 0; kk2 < 2; kk2++) {                      \
      _Pragma("unroll") for (int m2 = 0; m2 < 8; m2++) {                       \
        int r = m2 * 16 + fr, q = kk2 * 4 + fq;                                \
        bf16x8 af = *(const bf16x8*)&lA[B][r * 64 + (q ^ (r & 7)) * 8];        \
        acc[m2][0] = mfma_bf16(af, fb[0][kk2], acc[m2][0]);                    \
        acc[m2][1] = mfma_bf16(af, fb[1][kk2], acc[m2][1]);                    \
      }                                                                        \
    } }

  DN_GLA(0, 0);
  DN_LOADB(0);
  __syncthreads();
  DN_CVTB();
  for (int kk = 0; kk < 16; kk += 2) {
    DN_GLA(1, (kk + 1) * 64);
    DN_LOADB((kk + 1) * 64);
    DN_COMP(0);
    __syncthreads();
    DN_CVTB();
    if (kk + 2 < 16) { DN_GLA(0, (kk + 2) * 64); DN_LOADB((kk + 2) * 64); }
    DN_COMP(1);
    __syncthreads();
    if (kk + 2 < 16) DN_CVTB();
  }
#undef DN_GLA
#undef DN_LOADB
#undef DN_CVTB
#undef DN_COMP

  // epilogue: out[token] += w * val
  #pragma unroll
  for (int m2 = 0; m2 < 8; m2++)
    #pragma unroll
    for (int q = 0; q < 4; q++) {
      int row = m0 + m2 * 16 + fq * 4 + q;
      int p = perm[row];
      if (p < 0) continue;
      int t = p >> 1;
      float w = rw[p];
      #pragma unroll
      for (int n2 = 0; n2 < 2; n2++) {
        int col = n0 + wv * 32 + n2 * 16 + fr;
        atomicAdd(&out[(size_t)t * HID + col], acc[m2][n2][q] * w);
      }
    }
}

extern "C" void kernel_launch(void* const* d_in, const int* in_sizes, int n_in,
                              void* d_out, int out_size, void* d_ws, size_t ws_size,
                              hipStream_t stream) {
  const float* x   = (const float*)d_in[0];
  const float* rw  = (const float*)d_in[1];
  const int*   sel = (const int*)d_in[2];
  const float* gw  = (const float*)d_in[4];
  const float* uw  = (const float*)d_in[5];
  const float* dw  = (const float*)d_in[6];
  float* out = (float*)d_out;

  char* ws = (char*)d_ws;
  int*  hdr  = (int*)ws;                          // seg_base[9]
  int*  perm = (int*)(ws + 1024);                 // PERM_MAX ints
  u16*  xb   = (u16*)(ws + (1 << 16));            // 2M bf16 = 4 MiB
  u16*  hbuf = xb + (2 << 20);                    // 5120*1024 bf16 = 10 MiB

  k_prep <<<dim3(1024), dim3(256), 0, stream>>>(x, xb, out);
  k_route<<<dim3(1),    dim3(256), 0, stream>>>(sel, hdr, perm);
  k_gateup<<<dim3(16 * MT_MAX), dim3(256), 0, stream>>>(xb, gw, uw, hdr, perm, hbuf);
  k_down  <<<dim3(8 * MT_MAX),  dim3(256), 0, stream>>>(hbuf, dw, hdr, perm, rw, out);
}